// Round 1
// baseline (1313.368 us; speedup 1.0000x reference)
//
#include <hip/hip_runtime.h>
#include <hip/hip_bf16.h>
#include <math.h>

#define N_NODES   100000
#define N_EDGES   3200000
#define IN_DIM    128
#define HID       64
#define OUT_DIM   10
#define N_GRAPHS  64

#define SCAN_CHUNK 1024   // elements per scan block (256 threads x 4)
#define N_SCAN_BLOCKS ((N_NODES + SCAN_CHUNK - 1) / SCAN_CHUNK)  // 98

// ---------------------------------------------------------------- CSR build
__global__ __launch_bounds__(256) void count_edges(const int* __restrict__ rows,
                                                   int* __restrict__ cnt) {
    int e = blockIdx.x * 256 + threadIdx.x;
    if (e < N_EDGES) atomicAdd(&cnt[rows[e]], 1);
}

// Per-block exclusive scan (256 thr x 4 elems), block totals to blk[]
__global__ __launch_bounds__(256) void scan_blocks(const int* __restrict__ cnt,
                                                   int* __restrict__ out,
                                                   int* __restrict__ blk) {
    __shared__ int sdata[256];
    int t = threadIdx.x;
    int base = blockIdx.x * SCAN_CHUNK + t * 4;
    int v[4];
#pragma unroll
    for (int i = 0; i < 4; i++) {
        int idx = base + i;
        v[i] = (idx < N_NODES) ? cnt[idx] : 0;
    }
    int s = v[0] + v[1] + v[2] + v[3];
    sdata[t] = s;
    __syncthreads();
    for (int off = 1; off < 256; off <<= 1) {
        int x = (t >= off) ? sdata[t - off] : 0;
        __syncthreads();
        sdata[t] += x;
        __syncthreads();
    }
    int excl = sdata[t] - s;
#pragma unroll
    for (int i = 0; i < 4; i++) {
        int idx = base + i;
        if (idx < N_NODES) { out[idx] = excl; excl += v[i]; }
    }
    if (t == 255) blk[blockIdx.x] = sdata[255];
}

// Exclusive scan of the (<=128) block totals, in place
__global__ __launch_bounds__(128) void scan_totals(int* __restrict__ blk, int nb) {
    __shared__ int sdata[128];
    int t = threadIdx.x;
    int v = (t < nb) ? blk[t] : 0;
    sdata[t] = v;
    __syncthreads();
    for (int off = 1; off < 128; off <<= 1) {
        int x = (t >= off) ? sdata[t - off] : 0;
        __syncthreads();
        sdata[t] += x;
        __syncthreads();
    }
    if (t < nb) blk[t] = sdata[t] - v;
}

__global__ __launch_bounds__(256) void scan_add(int* __restrict__ row_ptr,
                                                const int* __restrict__ blk,
                                                int* __restrict__ cursor) {
    int i = blockIdx.x * 256 + threadIdx.x;
    if (i < N_NODES) {
        int v = row_ptr[i] + blk[i >> 10];
        row_ptr[i] = v;
        cursor[i]  = v;
    }
    if (i == 0) row_ptr[N_NODES] = N_EDGES;
}

__global__ __launch_bounds__(256) void scatter_edges(const int* __restrict__ rows,
                                                     const int* __restrict__ cols,
                                                     const float* __restrict__ vals,
                                                     int* __restrict__ cursor,
                                                     int* __restrict__ cols_s,
                                                     float* __restrict__ vals_s) {
    int e = blockIdx.x * 256 + threadIdx.x;
    if (e < N_EDGES) {
        int r = rows[e];
        int pos = atomicAdd(&cursor[r], 1);
        cols_s[pos] = cols[e];
        vals_s[pos] = vals[e];
    }
}

// ------------------------------------------------------------------- GEMM
// H[n][c] = sum_k X[n][k] * W[c][k] + b[c].  Thread = one row; W accessed
// wave-uniformly -> s_load; X via float4 (row-major, L1/L2 absorbs stride).
template <int IN>
__global__ __launch_bounds__(256) void gemm_bias(const float* __restrict__ X,
                                                 const float* __restrict__ W,
                                                 const float* __restrict__ B,
                                                 float* __restrict__ H) {
    int row = blockIdx.x * 256 + threadIdx.x;
    if (row >= N_NODES) return;
    float acc[HID];
#pragma unroll
    for (int c = 0; c < HID; c++) acc[c] = B[c];
    const float4* X4 = reinterpret_cast<const float4*>(X + (size_t)row * IN);
    for (int k0 = 0; k0 < IN; k0 += 32) {
        float x[32];
#pragma unroll
        for (int i = 0; i < 8; i++) {
            float4 t = X4[(k0 >> 2) + i];
            x[i * 4 + 0] = t.x; x[i * 4 + 1] = t.y;
            x[i * 4 + 2] = t.z; x[i * 4 + 3] = t.w;
        }
#pragma unroll
        for (int c = 0; c < HID; c++) {
            const float* w = W + c * IN + k0;
#pragma unroll
            for (int k = 0; k < 32; k++) acc[c] += x[k] * w[k];
        }
    }
    float4* out = reinterpret_cast<float4*>(H + (size_t)row * HID);
#pragma unroll
    for (int c = 0; c < HID; c += 4) {
        float4 o; o.x = acc[c]; o.y = acc[c+1]; o.z = acc[c+2]; o.w = acc[c+3];
        out[c >> 2] = o;
    }
}

// ------------------------------------------------------------------- SpMM
// Pull-style: one wave per destination row, lane = feature.
// MODE 1: Xout = relu(A h); Hsum  = Xout      (layer 1)
// MODE 2: Xout = relu(A h); Hsum += Xout      (layer 2)
// MODE 3:                   Hsum += relu(A h) (layer 3)
template <int MODE>
__global__ __launch_bounds__(256) void spmm_relu(const int* __restrict__ row_ptr,
                                                 const int* __restrict__ cols_s,
                                                 const float* __restrict__ vals_s,
                                                 const float* __restrict__ Hin,
                                                 float* __restrict__ Xout,
                                                 float* __restrict__ Hsum) {
    int wid  = (blockIdx.x * 256 + threadIdx.x) >> 6;
    int lane = threadIdx.x & 63;
    if (wid >= N_NODES) return;
    int r = __builtin_amdgcn_readfirstlane(wid);  // force wave-uniform -> s_loads
    int start = row_ptr[r];
    int end   = row_ptr[r + 1];
    float acc = 0.f;
    int e = start;
    for (; e + 4 <= end; e += 4) {
        int   c0 = cols_s[e],     c1 = cols_s[e + 1];
        int   c2 = cols_s[e + 2], c3 = cols_s[e + 3];
        float v0 = vals_s[e],     v1 = vals_s[e + 1];
        float v2 = vals_s[e + 2], v3 = vals_s[e + 3];
        float h0 = Hin[c0 * HID + lane];
        float h1 = Hin[c1 * HID + lane];
        float h2 = Hin[c2 * HID + lane];
        float h3 = Hin[c3 * HID + lane];
        acc += v0 * h0; acc += v1 * h1; acc += v2 * h2; acc += v3 * h3;
    }
    for (; e < end; e++) acc += vals_s[e] * Hin[cols_s[e] * HID + lane];
    float val = fmaxf(acc, 0.f);
    int idx = r * HID + lane;
    if (MODE == 1)      { Xout[idx] = val; Hsum[idx] = val; }
    else if (MODE == 2) { Xout[idx] = val; Hsum[idx] += val; }
    else                { Hsum[idx] += val; }
}

// ------------------------------------------------------------------- Pool
__global__ __launch_bounds__(128) void find_starts(const int* __restrict__ batch,
                                                   int* __restrict__ starts) {
    int g = threadIdx.x;
    if (g > N_GRAPHS) return;
    if (g == N_GRAPHS) { starts[g] = N_NODES; return; }
    int lo = 0, hi = N_NODES;
    while (lo < hi) {
        int mid = (lo + hi) >> 1;
        if (batch[mid] < g) lo = mid + 1; else hi = mid;
    }
    starts[g] = lo;
}

__global__ __launch_bounds__(256) void pool_kernel(const float* __restrict__ Hsum,
                                                   const int* __restrict__ starts,
                                                   float* __restrict__ pooled) {
    __shared__ float red[4][HID];
    int g = blockIdx.x;
    int lane = threadIdx.x & 63;
    int w = threadIdx.x >> 6;
    int s = starts[g], epos = starts[g + 1];
    float acc = 0.f;
    for (int n = s + w; n < epos; n += 4) acc += Hsum[(size_t)n * HID + lane];
    red[w][lane] = acc;
    __syncthreads();
    if (w == 0) {
        float tot = red[0][lane] + red[1][lane] + red[2][lane] + red[3][lane];
        int cntg = epos - s;
        float denom = 3.0f * (float)(cntg > 1 ? cntg : 1);
        pooled[g * HID + lane] = tot / denom;
    }
}

// ------------------------------------------------------------------- Head
__global__ __launch_bounds__(64) void head_kernel(const float* __restrict__ pooled,
                                                  const float* __restrict__ Wout,
                                                  const float* __restrict__ bout,
                                                  float* __restrict__ out) {
    int g = blockIdx.x;
    int t = threadIdx.x;
    __shared__ float pr[HID];
    __shared__ float lg[OUT_DIM];
    __shared__ float mx, sm;
    pr[t] = pooled[g * HID + t];
    __syncthreads();
    if (t < OUT_DIM) {
        float a = bout[t];
        for (int k = 0; k < HID; k++) a += pr[k] * Wout[t * HID + k];
        lg[t] = a;
    }
    __syncthreads();
    if (t == 0) {
        float m = lg[0];
        for (int j = 1; j < OUT_DIM; j++) m = fmaxf(m, lg[j]);
        float s = 0.f;
        for (int j = 0; j < OUT_DIM; j++) s += expf(lg[j] - m);
        mx = m; sm = s;
    }
    __syncthreads();
    if (t < OUT_DIM) out[g * OUT_DIM + t] = expf(lg[t] - mx) / sm;
}

// ---------------------------------------------------------------- launcher
extern "C" void kernel_launch(void* const* d_in, const int* in_sizes, int n_in,
                              void* d_out, int out_size, void* d_ws, size_t ws_size,
                              hipStream_t stream) {
    const float* X    = (const float*)d_in[0];
    const float* vals = (const float*)d_in[1];
    const float* W1   = (const float*)d_in[2];
    const float* b1   = (const float*)d_in[3];
    const float* W2   = (const float*)d_in[4];
    const float* b2   = (const float*)d_in[5];
    const float* W3   = (const float*)d_in[6];
    const float* b3   = (const float*)d_in[7];
    const float* Wout = (const float*)d_in[8];
    const float* bout = (const float*)d_in[9];
    const int*   rows = (const int*)d_in[10];
    const int*   cols = (const int*)d_in[11];
    const int*   batch= (const int*)d_in[12];
    float* out = (float*)d_out;

    // workspace carve (256B aligned)
    char* p = (char*)d_ws;
    auto carve = [&](size_t bytes) {
        void* q = (void*)p;
        p += (bytes + 255) & ~(size_t)255;
        return q;
    };
    float* h      = (float*)carve((size_t)N_NODES * HID * 4);
    float* Xc     = (float*)carve((size_t)N_NODES * HID * 4);
    float* hsum   = (float*)carve((size_t)N_NODES * HID * 4);
    int*   cnt    = (int*)  carve((size_t)N_NODES * 4);
    int*   row_ptr= (int*)  carve((size_t)(N_NODES + 1) * 4);
    int*   cursor = (int*)  carve((size_t)N_NODES * 4);
    int*   blk    = (int*)  carve(128 * 4);
    int*   starts = (int*)  carve((N_GRAPHS + 1) * 4);
    float* pooled = (float*)carve(N_GRAPHS * HID * 4);
    int*   cols_s = (int*)  carve((size_t)N_EDGES * 4);
    float* vals_s = (float*)carve((size_t)N_EDGES * 4);
    (void)ws_size; (void)in_sizes; (void)n_in; (void)out_size;

    // ---- CSR build (re-done every call; ws is poisoned between calls)
    hipMemsetAsync(cnt, 0, (size_t)N_NODES * 4, stream);
    count_edges<<<(N_EDGES + 255) / 256, 256, 0, stream>>>(rows, cnt);
    scan_blocks<<<N_SCAN_BLOCKS, 256, 0, stream>>>(cnt, row_ptr, blk);
    scan_totals<<<1, 128, 0, stream>>>(blk, N_SCAN_BLOCKS);
    scan_add<<<(N_NODES + 255) / 256, 256, 0, stream>>>(row_ptr, blk, cursor);
    scatter_edges<<<(N_EDGES + 255) / 256, 256, 0, stream>>>(rows, cols, vals,
                                                             cursor, cols_s, vals_s);

    const int gemm_grid = (N_NODES + 255) / 256;
    const int spmm_grid = (N_NODES + 3) / 4;   // 4 waves/block, 1 row/wave

    // ---- layer 1
    gemm_bias<IN_DIM><<<gemm_grid, 256, 0, stream>>>(X, W1, b1, h);
    spmm_relu<1><<<spmm_grid, 256, 0, stream>>>(row_ptr, cols_s, vals_s, h, Xc, hsum);
    // ---- layer 2
    gemm_bias<HID><<<gemm_grid, 256, 0, stream>>>(Xc, W2, b2, h);
    spmm_relu<2><<<spmm_grid, 256, 0, stream>>>(row_ptr, cols_s, vals_s, h, Xc, hsum);
    // ---- layer 3
    gemm_bias<HID><<<gemm_grid, 256, 0, stream>>>(Xc, W3, b3, h);
    spmm_relu<3><<<spmm_grid, 256, 0, stream>>>(row_ptr, cols_s, vals_s, h, Xc, hsum);

    // ---- pool + head
    find_starts<<<1, 128, 0, stream>>>(batch, starts);
    pool_kernel<<<N_GRAPHS, 256, 0, stream>>>(hsum, starts, pooled);
    head_kernel<<<N_GRAPHS, 64, 0, stream>>>(pooled, Wout, bout, out);
}

// Round 2
// 1020.601 us; speedup vs baseline: 1.2869x; 1.2869x over previous
//
#include <hip/hip_runtime.h>
#include <hip/hip_bf16.h>
#include <math.h>

#define N_NODES   100000
#define N_EDGES   3200000
#define IN_DIM    128
#define HID       64
#define OUT_DIM   10
#define N_GRAPHS  64

#define SCAN_CHUNK 1024   // elements per scan block (256 threads x 4)
#define N_SCAN_BLOCKS ((N_NODES + SCAN_CHUNK - 1) / SCAN_CHUNK)  // 98

typedef unsigned long long ull;

// ---------------------------------------------------------------- CSR build
__global__ __launch_bounds__(256) void count_edges(const int* __restrict__ rows,
                                                   int* __restrict__ cnt) {
    int e = blockIdx.x * 256 + threadIdx.x;
    if (e < N_EDGES) atomicAdd(&cnt[rows[e]], 1);
}

__global__ __launch_bounds__(256) void scan_blocks(const int* __restrict__ cnt,
                                                   int* __restrict__ out,
                                                   int* __restrict__ blk) {
    __shared__ int sdata[256];
    int t = threadIdx.x;
    int base = blockIdx.x * SCAN_CHUNK + t * 4;
    int v[4];
#pragma unroll
    for (int i = 0; i < 4; i++) {
        int idx = base + i;
        v[i] = (idx < N_NODES) ? cnt[idx] : 0;
    }
    int s = v[0] + v[1] + v[2] + v[3];
    sdata[t] = s;
    __syncthreads();
    for (int off = 1; off < 256; off <<= 1) {
        int x = (t >= off) ? sdata[t - off] : 0;
        __syncthreads();
        sdata[t] += x;
        __syncthreads();
    }
    int excl = sdata[t] - s;
#pragma unroll
    for (int i = 0; i < 4; i++) {
        int idx = base + i;
        if (idx < N_NODES) { out[idx] = excl; excl += v[i]; }
    }
    if (t == 255) blk[blockIdx.x] = sdata[255];
}

__global__ __launch_bounds__(128) void scan_totals(int* __restrict__ blk, int nb) {
    __shared__ int sdata[128];
    int t = threadIdx.x;
    int v = (t < nb) ? blk[t] : 0;
    sdata[t] = v;
    __syncthreads();
    for (int off = 1; off < 128; off <<= 1) {
        int x = (t >= off) ? sdata[t - off] : 0;
        __syncthreads();
        sdata[t] += x;
        __syncthreads();
    }
    if (t < nb) blk[t] = sdata[t] - v;
}

__global__ __launch_bounds__(256) void scan_add(int* __restrict__ row_ptr,
                                                const int* __restrict__ blk,
                                                int* __restrict__ cursor) {
    int i = blockIdx.x * 256 + threadIdx.x;
    if (i < N_NODES) {
        int v = row_ptr[i] + blk[i >> 10];
        row_ptr[i] = v;
        cursor[i]  = v;
    }
    if (i == 0) row_ptr[N_NODES] = N_EDGES;
}

// Pack (col, val) into one 8B element -> single random store per edge
// (was two 4B stores to two distant arrays = 2 dirty lines/edge).
__global__ __launch_bounds__(256) void scatter_edges(const int* __restrict__ rows,
                                                     const int* __restrict__ cols,
                                                     const float* __restrict__ vals,
                                                     int* __restrict__ cursor,
                                                     ull* __restrict__ edges) {
    int e = blockIdx.x * 256 + threadIdx.x;
    if (e < N_EDGES) {
        int r = rows[e];
        int pos = atomicAdd(&cursor[r], 1);
        ull pk = ((ull)__float_as_uint(vals[e]) << 32) | (unsigned)cols[e];
        edges[pos] = pk;
    }
}

// ------------------------------------------------------------------- GEMM
// H[n][c] = sum_k X[n][k] * W[c][k] + b[c].
// Thread = one row x CPT channels; blockIdx.y picks the channel group so
// W stays wave-uniform (scalar loads). 4-way channel split quadruples the
// wave count (6 -> 24 waves/CU) to fix the occupancy ceiling seen in R1.
template <int IN, int CPT>
__global__ __launch_bounds__(256) void gemm_bias(const float* __restrict__ X,
                                                 const float* __restrict__ W,
                                                 const float* __restrict__ B,
                                                 float* __restrict__ H) {
    int row = blockIdx.x * 256 + threadIdx.x;
    int c0 = blockIdx.y * CPT;
    if (row >= N_NODES) return;
    float acc[CPT];
#pragma unroll
    for (int c = 0; c < CPT; c++) acc[c] = B[c0 + c];
    const float4* X4 = reinterpret_cast<const float4*>(X + (size_t)row * IN);
    for (int k0 = 0; k0 < IN; k0 += 16) {
        float x[16];
#pragma unroll
        for (int i = 0; i < 4; i++) {
            float4 t = X4[(k0 >> 2) + i];
            x[i * 4 + 0] = t.x; x[i * 4 + 1] = t.y;
            x[i * 4 + 2] = t.z; x[i * 4 + 3] = t.w;
        }
#pragma unroll
        for (int c = 0; c < CPT; c++) {
            const float* w = W + (c0 + c) * IN + k0;
#pragma unroll
            for (int k = 0; k < 16; k++) acc[c] += x[k] * w[k];
        }
    }
    float4* out = reinterpret_cast<float4*>(H + (size_t)row * HID + c0);
#pragma unroll
    for (int c = 0; c < CPT; c += 4) {
        float4 o; o.x = acc[c]; o.y = acc[c+1]; o.z = acc[c+2]; o.w = acc[c+3];
        out[c >> 2] = o;
    }
}

// ------------------------------------------------------------------- SpMM
// Pull-style: one wave per destination row, lane = feature. 8-deep edge
// unroll for outstanding-load ILP; edges are packed 8B (col,val).
template <int MODE>
__global__ __launch_bounds__(256) void spmm_relu(const int* __restrict__ row_ptr,
                                                 const ull* __restrict__ edges,
                                                 const float* __restrict__ Hin,
                                                 float* __restrict__ Xout,
                                                 float* __restrict__ Hsum) {
    int wid  = (blockIdx.x * 256 + threadIdx.x) >> 6;
    int lane = threadIdx.x & 63;
    if (wid >= N_NODES) return;
    int r = __builtin_amdgcn_readfirstlane(wid);  // wave-uniform -> s_loads
    int start = row_ptr[r];
    int end   = row_ptr[r + 1];
    float acc = 0.f;
    int e = start;
    for (; e + 8 <= end; e += 8) {
        ull p[8];
#pragma unroll
        for (int i = 0; i < 8; i++) p[i] = edges[e + i];
        float h[8];
#pragma unroll
        for (int i = 0; i < 8; i++) {
            int c = (int)(unsigned)(p[i] & 0xffffffffu);
            h[i] = Hin[c * HID + lane];
        }
#pragma unroll
        for (int i = 0; i < 8; i++) {
            float v = __uint_as_float((unsigned)(p[i] >> 32));
            acc += v * h[i];
        }
    }
    for (; e < end; e++) {
        ull p = edges[e];
        int c = (int)(unsigned)(p & 0xffffffffu);
        float v = __uint_as_float((unsigned)(p >> 32));
        acc += v * Hin[c * HID + lane];
    }
    float val = fmaxf(acc, 0.f);
    int idx = r * HID + lane;
    if (MODE == 1)      { Xout[idx] = val; Hsum[idx] = val; }
    else if (MODE == 2) { Xout[idx] = val; Hsum[idx] += val; }
    else                { Hsum[idx] += val; }
}

// ------------------------------------------------------------------- Pool
__global__ __launch_bounds__(128) void find_starts(const int* __restrict__ batch,
                                                   int* __restrict__ starts) {
    int g = threadIdx.x;
    if (g > N_GRAPHS) return;
    if (g == N_GRAPHS) { starts[g] = N_NODES; return; }
    int lo = 0, hi = N_NODES;
    while (lo < hi) {
        int mid = (lo + hi) >> 1;
        if (batch[mid] < g) lo = mid + 1; else hi = mid;
    }
    starts[g] = lo;
}

__global__ __launch_bounds__(256) void pool_kernel(const float* __restrict__ Hsum,
                                                   const int* __restrict__ starts,
                                                   float* __restrict__ pooled) {
    __shared__ float red[4][HID];
    int g = blockIdx.x;
    int lane = threadIdx.x & 63;
    int w = threadIdx.x >> 6;
    int s = starts[g], epos = starts[g + 1];
    float acc = 0.f;
    for (int n = s + w; n < epos; n += 4) acc += Hsum[(size_t)n * HID + lane];
    red[w][lane] = acc;
    __syncthreads();
    if (w == 0) {
        float tot = red[0][lane] + red[1][lane] + red[2][lane] + red[3][lane];
        int cntg = epos - s;
        float denom = 3.0f * (float)(cntg > 1 ? cntg : 1);
        pooled[g * HID + lane] = tot / denom;
    }
}

// ------------------------------------------------------------------- Head
__global__ __launch_bounds__(64) void head_kernel(const float* __restrict__ pooled,
                                                  const float* __restrict__ Wout,
                                                  const float* __restrict__ bout,
                                                  float* __restrict__ out) {
    int g = blockIdx.x;
    int t = threadIdx.x;
    __shared__ float pr[HID];
    __shared__ float lg[OUT_DIM];
    __shared__ float mx, sm;
    pr[t] = pooled[g * HID + t];
    __syncthreads();
    if (t < OUT_DIM) {
        float a = bout[t];
        for (int k = 0; k < HID; k++) a += pr[k] * Wout[t * HID + k];
        lg[t] = a;
    }
    __syncthreads();
    if (t == 0) {
        float m = lg[0];
        for (int j = 1; j < OUT_DIM; j++) m = fmaxf(m, lg[j]);
        float s = 0.f;
        for (int j = 0; j < OUT_DIM; j++) s += expf(lg[j] - m);
        mx = m; sm = s;
    }
    __syncthreads();
    if (t < OUT_DIM) out[g * OUT_DIM + t] = expf(lg[t] - mx) / sm;
}

// ---------------------------------------------------------------- launcher
extern "C" void kernel_launch(void* const* d_in, const int* in_sizes, int n_in,
                              void* d_out, int out_size, void* d_ws, size_t ws_size,
                              hipStream_t stream) {
    const float* X    = (const float*)d_in[0];
    const float* vals = (const float*)d_in[1];
    const float* W1   = (const float*)d_in[2];
    const float* b1   = (const float*)d_in[3];
    const float* W2   = (const float*)d_in[4];
    const float* b2   = (const float*)d_in[5];
    const float* W3   = (const float*)d_in[6];
    const float* b3   = (const float*)d_in[7];
    const float* Wout = (const float*)d_in[8];
    const float* bout = (const float*)d_in[9];
    const int*   rows = (const int*)d_in[10];
    const int*   cols = (const int*)d_in[11];
    const int*   batch= (const int*)d_in[12];
    float* out = (float*)d_out;

    char* p = (char*)d_ws;
    auto carve = [&](size_t bytes) {
        void* q = (void*)p;
        p += (bytes + 255) & ~(size_t)255;
        return q;
    };
    float* h      = (float*)carve((size_t)N_NODES * HID * 4);
    float* Xc     = (float*)carve((size_t)N_NODES * HID * 4);
    float* hsum   = (float*)carve((size_t)N_NODES * HID * 4);
    int*   cnt    = (int*)  carve((size_t)N_NODES * 4);
    int*   row_ptr= (int*)  carve((size_t)(N_NODES + 1) * 4);
    int*   cursor = (int*)  carve((size_t)N_NODES * 4);
    int*   blk    = (int*)  carve(128 * 4);
    int*   starts = (int*)  carve((N_GRAPHS + 1) * 4);
    float* pooled = (float*)carve(N_GRAPHS * HID * 4);
    ull*   edges  = (ull*)  carve((size_t)N_EDGES * 8);
    (void)ws_size; (void)in_sizes; (void)n_in; (void)out_size;

    // ---- CSR build
    hipMemsetAsync(cnt, 0, (size_t)N_NODES * 4, stream);
    count_edges<<<(N_EDGES + 255) / 256, 256, 0, stream>>>(rows, cnt);
    scan_blocks<<<N_SCAN_BLOCKS, 256, 0, stream>>>(cnt, row_ptr, blk);
    scan_totals<<<1, 128, 0, stream>>>(blk, N_SCAN_BLOCKS);
    scan_add<<<(N_NODES + 255) / 256, 256, 0, stream>>>(row_ptr, blk, cursor);
    scatter_edges<<<(N_EDGES + 255) / 256, 256, 0, stream>>>(rows, cols, vals,
                                                             cursor, edges);

    const dim3 gemm_grid((N_NODES + 255) / 256, HID / 16);  // 16 channels/thread
    const int  spmm_grid = (N_NODES + 3) / 4;               // 4 waves/block

    // ---- layer 1
    gemm_bias<IN_DIM, 16><<<gemm_grid, 256, 0, stream>>>(X, W1, b1, h);
    spmm_relu<1><<<spmm_grid, 256, 0, stream>>>(row_ptr, edges, h, Xc, hsum);
    // ---- layer 2
    gemm_bias<HID, 16><<<gemm_grid, 256, 0, stream>>>(Xc, W2, b2, h);
    spmm_relu<2><<<spmm_grid, 256, 0, stream>>>(row_ptr, edges, h, Xc, hsum);
    // ---- layer 3
    gemm_bias<HID, 16><<<gemm_grid, 256, 0, stream>>>(Xc, W3, b3, h);
    spmm_relu<3><<<spmm_grid, 256, 0, stream>>>(row_ptr, edges, h, Xc, hsum);

    // ---- pool + head
    find_starts<<<1, 128, 0, stream>>>(batch, starts);
    pool_kernel<<<N_GRAPHS, 256, 0, stream>>>(hsum, starts, pooled);
    head_kernel<<<N_GRAPHS, 64, 0, stream>>>(pooled, Wout, bout, out);
}